// Round 1
// baseline (4934.299 us; speedup 1.0000x reference)
//
#include <hip/hip_runtime.h>

// GraphLayer: B=16384, F=50, E=64, all fp32.
//   h_out[b,f,i] = sum_j W_out[f,i,j] * h[b,f,j]
//   aggr[b,f,e]  = sum_g g[b,f,g] * h_out[b,g,e]
//   a[b,f,i]     = sum_j W_in[f,i,j] * aggr[b,f,j] + bias[i]
//
// Round 1: 3-kernel fp32 split, no workspace (intermediates live in d_out,
// stage2/3 are block-local in-place). Memory floor for this split ~226 us.

static constexpr int Bz  = 16384;
static constexpr int Ff  = 50;
static constexpr int Ee  = 64;
static constexpr int BT  = 128;   // batch tile for per-field GEMM
static constexpr int LDW = 68;    // padded LDS row stride (floats, 16B-aligned, 68%32=4)
static constexpr int GP  = 56;    // padded field count for stage2 (50 -> 56, /8)

__device__ __forceinline__ void fma4(float4& a, float s, const float4& v) {
    a.x += s * v.x; a.y += s * v.y; a.z += s * v.z; a.w += s * v.w;
}

// dst[b,f,i] = sum_j W[f,i,j]*src[b,f,j] (+ bias[i]).  In-place (src==dst) safe:
// all global reads complete before the barrier; stores happen after.
__global__ __launch_bounds__(256)
void field_gemm(const float* __restrict__ src, float* __restrict__ dst,
                const float* __restrict__ W, const float* __restrict__ bias) {
    __shared__ float W_lds[Ee * LDW];   // 64 x 68 floats = 17.4 KB
    __shared__ float h_lds[BT * LDW];   // 128 x 68 floats = 34.8 KB
    const int f  = blockIdx.y;
    const int b0 = blockIdx.x * BT;
    const int t  = threadIdx.x;

    // stage W[f] (4096 floats), coalesced
    const float* Wf = W + f * Ee * Ee;
#pragma unroll
    for (int k = 0; k < 16; ++k) {
        int idx = k * 256 + t;
        W_lds[(idx >> 6) * LDW + (idx & 63)] = Wf[idx];
    }
    // stage src tile (128 batches x 64), coalesced per 64-row
#pragma unroll
    for (int k = 0; k < (BT * Ee) / 256; ++k) {   // 32 iters
        int idx = k * 256 + t;
        int bb = idx >> 6, j = idx & 63;
        h_lds[bb * LDW + j] = src[(b0 + bb) * (Ff * Ee) + f * Ee + j];
    }
    __syncthreads();

    // thread computes 4 i's x 8 batches; i = ti + 16*ii, bb = tb + 16*kb
    const int ti = t & 15;
    const int tb = t >> 4;
    float acc[4][8];
#pragma unroll
    for (int ii = 0; ii < 4; ++ii)
#pragma unroll
        for (int kb = 0; kb < 8; ++kb) acc[ii][kb] = 0.f;

#pragma unroll
    for (int j0 = 0; j0 < Ee; j0 += 4) {
        float4 w4[4], h4[8];
#pragma unroll
        for (int ii = 0; ii < 4; ++ii)
            w4[ii] = *(const float4*)&W_lds[(ti + ii * 16) * LDW + j0];
#pragma unroll
        for (int kb = 0; kb < 8; ++kb)
            h4[kb] = *(const float4*)&h_lds[(tb + kb * 16) * LDW + j0];
#pragma unroll
        for (int ii = 0; ii < 4; ++ii)
#pragma unroll
            for (int kb = 0; kb < 8; ++kb) {
                acc[ii][kb] += w4[ii].x * h4[kb].x;
                acc[ii][kb] += w4[ii].y * h4[kb].y;
                acc[ii][kb] += w4[ii].z * h4[kb].z;
                acc[ii][kb] += w4[ii].w * h4[kb].w;
            }
    }

#pragma unroll
    for (int ii = 0; ii < 4; ++ii) {
        int i = ti + ii * 16;
        float bv = bias ? bias[i] : 0.0f;
#pragma unroll
        for (int kb = 0; kb < 8; ++kb) {
            int bb = tb + kb * 16;
            dst[(b0 + bb) * (Ff * Ee) + f * Ee + i] = acc[ii][kb] + bv;
        }
    }
}

// aggr[b,f,e] = sum_g g[b,f,g] * ho[b,g,e], written in place over ho (d_out).
// One block per batch; ho[b] and g[b] fully staged in LDS before overwrite.
__global__ __launch_bounds__(256)
void aggr_inplace(const float* __restrict__ g, float* __restrict__ ho) {
    __shared__ float ho_lds[GP * LDW];   // 56 x 68 = 15.2 KB (rows 50..55 zero)
    __shared__ float g_lds[Ff * GP];     // 50 x 56 = 11.2 KB (cols 50..55 zero)
    const int b = blockIdx.x;
    const int t = threadIdx.x;
    const float* gb = g + (size_t)b * (Ff * Ff);
    float*       hb = ho + (size_t)b * (Ff * Ee);

#pragma unroll
    for (int k = 0; k < 13; ++k) {
        int idx = k * 256 + t;
        if (idx < Ff * Ee)
            ho_lds[(idx >> 6) * LDW + (idx & 63)] = hb[idx];
    }
#pragma unroll
    for (int k = 0; k < 2; ++k) {
        int q = k * 256 + t;
        if (q < (GP - Ff) * Ee)
            ho_lds[(Ff + (q >> 6)) * LDW + (q & 63)] = 0.f;
    }
#pragma unroll
    for (int k = 0; k < 11; ++k) {
        int idx = k * 256 + t;
        if (idx < Ff * GP) {
            int ff = idx / GP, gg = idx - ff * GP;
            g_lds[idx] = (gg < Ff) ? gb[ff * Ff + gg] : 0.f;
        }
    }
    __syncthreads();

    // thread: e-quad te*4, fields fR = tf + 16*kf (kf<4, guarded by fR<50)
    const int te = t & 15;
    const int tf = t >> 4;
    float4 acc[4];
#pragma unroll
    for (int q = 0; q < 4; ++q) acc[q] = make_float4(0.f, 0.f, 0.f, 0.f);

#pragma unroll
    for (int g0 = 0; g0 < GP; g0 += 8) {
        float4 ho4[8];
#pragma unroll
        for (int q = 0; q < 8; ++q)
            ho4[q] = *(const float4*)&ho_lds[(g0 + q) * LDW + te * 4];
#pragma unroll
        for (int kf = 0; kf < 4; ++kf) {
            int fR = tf + kf * 16;
            if (fR < Ff) {
                float4 ga  = *(const float4*)&g_lds[fR * GP + g0];
                float4 gb4 = *(const float4*)&g_lds[fR * GP + g0 + 4];
                fma4(acc[kf], ga.x,  ho4[0]);
                fma4(acc[kf], ga.y,  ho4[1]);
                fma4(acc[kf], ga.z,  ho4[2]);
                fma4(acc[kf], ga.w,  ho4[3]);
                fma4(acc[kf], gb4.x, ho4[4]);
                fma4(acc[kf], gb4.y, ho4[5]);
                fma4(acc[kf], gb4.z, ho4[6]);
                fma4(acc[kf], gb4.w, ho4[7]);
            }
        }
    }

#pragma unroll
    for (int kf = 0; kf < 4; ++kf) {
        int fR = tf + kf * 16;
        if (fR < Ff)
            *(float4*)&hb[fR * Ee + te * 4] = acc[kf];
    }
}

extern "C" void kernel_launch(void* const* d_in, const int* in_sizes, int n_in,
                              void* d_out, int out_size, void* d_ws, size_t ws_size,
                              hipStream_t stream) {
    const float* g     = (const float*)d_in[0];
    const float* h     = (const float*)d_in[1];
    const float* W_in  = (const float*)d_in[2];
    const float* W_out = (const float*)d_in[3];
    const float* bias  = (const float*)d_in[4];
    float* out = (float*)d_out;

    dim3 grid1(Bz / BT, Ff);
    // stage 1: h_out -> d_out
    field_gemm<<<grid1, 256, 0, stream>>>(h, out, W_out, nullptr);
    // stage 2: aggr, in place over d_out
    aggr_inplace<<<Bz, 256, 0, stream>>>(g, out);
    // stage 3: a = W_in * aggr + bias, in place over d_out
    field_gemm<<<grid1, 256, 0, stream>>>(out, out, W_in, bias);
}

// Round 2
// 696.611 us; speedup vs baseline: 7.0833x; 7.0833x over previous
//
#include <hip/hip_runtime.h>

// GraphLayer: B=16384, F=50, E=64, all fp32.
//   h_out[b,f,i] = sum_j W_out[f,i,j] * h[b,f,j]
//   aggr[b,f,e]  = sum_g g[b,f,g] * h_out[b,g,e]
//   a[b,f,i]     = sum_j W_in[f,i,j] * aggr[b,f,j] + bias[i]
//
// Round 2: same 3-kernel fp32 split as R1, but fix the register-spill
// catastrophe in field_gemm: R1's fully-unrolled K-loop hoisted ~768 floats
// of LDS loads -> VGPR=256 + ~4 GB of scratch spill traffic per dispatch.
// Fix: #pragma unroll 2 on the K-loop (live set ~128 regs) and
// __launch_bounds__(256,3) (3 waves/EU matches the 3-blocks/CU LDS limit,
// caps allocator at ~170 VGPRs).

static constexpr int Bz  = 16384;
static constexpr int Ff  = 50;
static constexpr int Ee  = 64;
static constexpr int BT  = 128;   // batch tile for per-field GEMM
static constexpr int LDW = 68;    // padded LDS row stride (floats, 16B-aligned)
static constexpr int GP  = 56;    // padded field count for stage2 (50 -> 56, /8)

__device__ __forceinline__ void fma4(float4& a, float s, const float4& v) {
    a.x += s * v.x; a.y += s * v.y; a.z += s * v.z; a.w += s * v.w;
}

// dst[b,f,i] = sum_j W[f,i,j]*src[b,f,j] (+ bias[i]).  In-place (src==dst) safe:
// all global reads complete before the barrier; stores happen after, and each
// (b,f,:) row is owned by exactly one block.
__global__ __launch_bounds__(256, 3)
void field_gemm(const float* __restrict__ src, float* __restrict__ dst,
                const float* __restrict__ W, const float* __restrict__ bias) {
    __shared__ float W_lds[Ee * LDW];   // 64 x 68 floats = 17.4 KB
    __shared__ float h_lds[BT * LDW];   // 128 x 68 floats = 34.8 KB
    const int f  = blockIdx.y;
    const int b0 = blockIdx.x * BT;
    const int t  = threadIdx.x;

    // stage W[f] (4096 floats), coalesced
    const float* Wf = W + f * Ee * Ee;
#pragma unroll
    for (int k = 0; k < 16; ++k) {
        int idx = k * 256 + t;
        W_lds[(idx >> 6) * LDW + (idx & 63)] = Wf[idx];
    }
    // stage src tile (128 batches x 64), coalesced per 64-float row
#pragma unroll
    for (int k = 0; k < (BT * Ee) / 256; ++k) {   // 32 iters
        int idx = k * 256 + t;
        int bb = idx >> 6, j = idx & 63;
        h_lds[bb * LDW + j] = src[(b0 + bb) * (Ff * Ee) + f * Ee + j];
    }
    __syncthreads();

    // thread computes 4 i's x 8 batches; i = ti + 16*ii, bb = tb + 16*kb
    const int ti = t & 15;
    const int tb = t >> 4;
    float acc[4][8];
#pragma unroll
    for (int ii = 0; ii < 4; ++ii)
#pragma unroll
        for (int kb = 0; kb < 8; ++kb) acc[ii][kb] = 0.f;

    // K loop: unroll limited to 2 to keep live set ~128 VGPRs (R1's full
    // unroll spilled: VGPR=256, ~4 GB scratch traffic, 2280 us/dispatch).
#pragma unroll 2
    for (int j0 = 0; j0 < Ee; j0 += 4) {
        float4 w4[4], h4[8];
#pragma unroll
        for (int ii = 0; ii < 4; ++ii)
            w4[ii] = *(const float4*)&W_lds[(ti + ii * 16) * LDW + j0];
#pragma unroll
        for (int kb = 0; kb < 8; ++kb)
            h4[kb] = *(const float4*)&h_lds[(tb + kb * 16) * LDW + j0];
#pragma unroll
        for (int ii = 0; ii < 4; ++ii)
#pragma unroll
            for (int kb = 0; kb < 8; ++kb) {
                acc[ii][kb] += w4[ii].x * h4[kb].x;
                acc[ii][kb] += w4[ii].y * h4[kb].y;
                acc[ii][kb] += w4[ii].z * h4[kb].z;
                acc[ii][kb] += w4[ii].w * h4[kb].w;
            }
    }

#pragma unroll
    for (int ii = 0; ii < 4; ++ii) {
        int i = ti + ii * 16;
        float bv = bias ? bias[i] : 0.0f;
#pragma unroll
        for (int kb = 0; kb < 8; ++kb) {
            int bb = tb + kb * 16;
            dst[(b0 + bb) * (Ff * Ee) + f * Ee + i] = acc[ii][kb] + bv;
        }
    }
}

// aggr[b,f,e] = sum_g g[b,f,g] * ho[b,g,e], written in place over ho (d_out).
// One block per batch; ho[b] and g[b] fully staged in LDS before overwrite.
__global__ __launch_bounds__(256)
void aggr_inplace(const float* __restrict__ g, float* __restrict__ ho) {
    __shared__ float ho_lds[GP * LDW];   // 56 x 68 = 15.2 KB (rows 50..55 zero)
    __shared__ float g_lds[Ff * GP];     // 50 x 56 = 11.2 KB (cols 50..55 zero)
    const int b = blockIdx.x;
    const int t = threadIdx.x;
    const float* gb = g + (size_t)b * (Ff * Ff);
    float*       hb = ho + (size_t)b * (Ff * Ee);

#pragma unroll
    for (int k = 0; k < 13; ++k) {
        int idx = k * 256 + t;
        if (idx < Ff * Ee)
            ho_lds[(idx >> 6) * LDW + (idx & 63)] = hb[idx];
    }
#pragma unroll
    for (int k = 0; k < 2; ++k) {
        int q = k * 256 + t;
        if (q < (GP - Ff) * Ee)
            ho_lds[(Ff + (q >> 6)) * LDW + (q & 63)] = 0.f;
    }
#pragma unroll
    for (int k = 0; k < 11; ++k) {
        int idx = k * 256 + t;
        if (idx < Ff * GP) {
            int ff = idx / GP, gg = idx - ff * GP;
            g_lds[idx] = (gg < Ff) ? gb[ff * Ff + gg] : 0.f;
        }
    }
    __syncthreads();

    // thread: e-quad te*4, fields fR = tf + 16*kf (kf<4, guarded by fR<50)
    const int te = t & 15;
    const int tf = t >> 4;
    float4 acc[4];
#pragma unroll
    for (int q = 0; q < 4; ++q) acc[q] = make_float4(0.f, 0.f, 0.f, 0.f);

#pragma unroll 2
    for (int g0 = 0; g0 < GP; g0 += 8) {
        float4 ho4[8];
#pragma unroll
        for (int q = 0; q < 8; ++q)
            ho4[q] = *(const float4*)&ho_lds[(g0 + q) * LDW + te * 4];
#pragma unroll
        for (int kf = 0; kf < 4; ++kf) {
            int fR = tf + kf * 16;
            if (fR < Ff) {
                float4 ga  = *(const float4*)&g_lds[fR * GP + g0];
                float4 gb4 = *(const float4*)&g_lds[fR * GP + g0 + 4];
                fma4(acc[kf], ga.x,  ho4[0]);
                fma4(acc[kf], ga.y,  ho4[1]);
                fma4(acc[kf], ga.z,  ho4[2]);
                fma4(acc[kf], ga.w,  ho4[3]);
                fma4(acc[kf], gb4.x, ho4[4]);
                fma4(acc[kf], gb4.y, ho4[5]);
                fma4(acc[kf], gb4.z, ho4[6]);
                fma4(acc[kf], gb4.w, ho4[7]);
            }
        }
    }

#pragma unroll
    for (int kf = 0; kf < 4; ++kf) {
        int fR = tf + kf * 16;
        if (fR < Ff)
            *(float4*)&hb[fR * Ee + te * 4] = acc[kf];
    }
}

extern "C" void kernel_launch(void* const* d_in, const int* in_sizes, int n_in,
                              void* d_out, int out_size, void* d_ws, size_t ws_size,
                              hipStream_t stream) {
    const float* g     = (const float*)d_in[0];
    const float* h     = (const float*)d_in[1];
    const float* W_in  = (const float*)d_in[2];
    const float* W_out = (const float*)d_in[3];
    const float* bias  = (const float*)d_in[4];
    float* out = (float*)d_out;

    dim3 grid1(Bz / BT, Ff);
    // stage 1: h_out -> d_out
    field_gemm<<<grid1, 256, 0, stream>>>(h, out, W_out, nullptr);
    // stage 2: aggr, in place over d_out
    aggr_inplace<<<Bz, 256, 0, stream>>>(g, out);
    // stage 3: a = W_in * aggr + bias, in place over d_out
    field_gemm<<<grid1, 256, 0, stream>>>(out, out, W_in, bias);
}